// Round 15
// baseline (111930.640 us; speedup 1.0000x reference)
//
#include <hip/hip_runtime.h>
#include <cstdint>
#include <cstddef>

typedef _Float16 h2v __attribute__((ext_vector_type(2)));
typedef _Float16 h4v __attribute__((ext_vector_type(4)));
typedef _Float16 h8v __attribute__((ext_vector_type(8)));

#define NEG_SLOPE 0.2f
#define BN_EPS 1e-5f
#define BM 64
#define BN 64
#define BK 16
#define GCHUNK 1024   // GRU pipeline chunk (steps); must be multiple of 8
#define NW0 40        // gi0 GEMM workers (h2-gather @ Wih0^T, K=515)
#define NW1 22        // gi1 GEMM workers (g0 @ Wih1^T, K=256)
#define NBLK (2 + NW0 + NW1)
#define LDS_POOL_BYTES 98304   // 96 KB: HW max 1 block/CU (validated round-11)

__device__ __forceinline__ float lrelu(float x) { return x > 0.f ? x : NEG_SLOPE * x; }

__device__ __forceinline__ unsigned fenc(float f) {
  unsigned b = __float_as_uint(f);
  return (b & 0x80000000u) ? ~b : (b | 0x80000000u);
}
__device__ __forceinline__ float fdec(unsigned u) {
  return (u & 0x80000000u) ? __uint_as_float(u & 0x7fffffffu) : __uint_as_float(~u);
}

// packed f16 fma: 2 MACs / lane / instr (v_pk_fma_f16, full rate)
__device__ __forceinline__ h2v pkfma(h2v a, h2v b, h2v c) {
#if __has_builtin(__builtin_elementwise_fma)
  return __builtin_elementwise_fma(a, b, c);
#else
  return a * b + c;
#endif
}

__device__ __forceinline__ float sigf(float x) { return 1.f / (1.f + __expf(-x)); }
__device__ __forceinline__ float tanhfast(float x) {
  x = fminf(fmaxf(x, -20.f), 20.f);
  float e = __expf(2.f * x);
  return (e - 1.f) / (e + 1.f);
}

// VALU-pipe quad butterflies (DPP quad_perm) — 4-lane K-quarter reduce off
// the DS pipe. xor1: perm [1,0,3,2]=0xB1; xor2: [2,3,0,1]=0x4E.
__device__ __forceinline__ float dpp_xor1(float x) {
  return __int_as_float(__builtin_amdgcn_mov_dpp(__float_as_int(x), 0xB1, 0xF, 0xF, true));
}
__device__ __forceinline__ float dpp_xor2(float x) {
  return __int_as_float(__builtin_amdgcn_mov_dpp(__float_as_int(x), 0x4E, 0xF, 0xF, true));
}

// Per-step barrier for the GRU scan: only LDS ordering is required for the
// h hand-off (LDS is CU-local). __syncthreads() would drain vmcnt(0) too,
// serializing the gi prefetch / gout store latency into the recurrence.
__device__ __forceinline__ void step_barrier() {
  __builtin_amdgcn_sched_barrier(0);
  asm volatile("s_waitcnt lgkmcnt(0)" ::: "memory");
  __builtin_amdgcn_s_barrier();
  __builtin_amdgcn_sched_barrier(0);
}

// ---------------- GAT layer 1 (rank-1 collapse) ----------------

__global__ __launch_bounds__(256) void k_prep_c(const float* __restrict__ W1,
                                                const float* __restrict__ as1,
                                                const float* __restrict__ ad1,
                                                float* __restrict__ c12) {
  __shared__ float r1[256], r2[256];
  int j = threadIdx.x;
  float wv = W1[j];
  r1[j] = wv * as1[j];
  r2[j] = wv * ad1[j];
  __syncthreads();
  for (int s = 128; s > 0; s >>= 1) {
    if (j < s) { r1[j] += r1[j + s]; r2[j] += r2[j + s]; }
    __syncthreads();
  }
  if (j == 0) { c12[0] = r1[0]; c12[1] = r2[0]; }
}

__global__ __launch_bounds__(256) void k_a1(const float* __restrict__ x, const float* __restrict__ c12,
                                            float* __restrict__ a1s, float* __restrict__ a1d, int N) {
  int i = blockIdx.x * 256 + threadIdx.x;
  if (i < N) {
    float xv = x[i];
    a1s[i] = c12[0] * xv;
    a1d[i] = c12[1] * xv;
  }
}

__global__ __launch_bounds__(256) void k_edge_max(const float* __restrict__ as_, const float* __restrict__ ad_,
                                                  unsigned* __restrict__ menc, const int* __restrict__ src,
                                                  const int* __restrict__ dst, int E, int N) {
  int i = blockIdx.x * 256 + threadIdx.x;
  if (i >= E + N) return;
  int s, d;
  if (i < E) { s = src[i]; d = dst[i]; } else { s = i - E; d = s; }
  float e = lrelu(as_[s] + ad_[d]);
  atomicMax(&menc[d], fenc(e));
}

__global__ __launch_bounds__(256) void k_gat1_edge_sum(const float* __restrict__ as_, const float* __restrict__ ad_,
                                                       const unsigned* __restrict__ menc, const int* __restrict__ src,
                                                       const int* __restrict__ dst, const float* __restrict__ x,
                                                       float* __restrict__ z, float* __restrict__ uacc, int E, int N) {
  int i = blockIdx.x * 256 + threadIdx.x;
  if (i >= E + N) return;
  int s, d;
  if (i < E) { s = src[i]; d = dst[i]; } else { s = i - E; d = s; }
  float e = lrelu(as_[s] + ad_[d]);
  float p = __expf(e - fdec(menc[d]));
  atomicAdd(&z[d], p);
  atomicAdd(&uacc[d], p * x[s]);
}

__global__ __launch_bounds__(256) void k_gat1_node(const float* __restrict__ uacc, const float* __restrict__ z1,
                                                   const float* __restrict__ W1, const float* __restrict__ b1,
                                                   const float* __restrict__ gamma, const float* __restrict__ beta,
                                                   const float* __restrict__ mean, const float* __restrict__ var,
                                                   float* __restrict__ h1) {
  int n = blockIdx.x, j = threadIdx.x;
  float u = uacc[n] / z1[n];
  float v = u * W1[j] + b1[j];
  v = (v - mean[j]) * rsqrtf(var[j] + BN_EPS) * gamma[j] + beta[j];
  h1[(size_t)n * 256 + j] = fmaxf(v, 0.f);
}

// ---------------- generic fp32 tiled GEMM: C[M,N] = A[M,K] * B[K,N] ----------------

__global__ __launch_bounds__(256) void k_gemm_f32(const float* __restrict__ A, const float* __restrict__ B,
                                                  float* __restrict__ C, int M, int N, int K) {
  __shared__ float As[BK][BM];
  __shared__ float Bs[BK][BN];
  int tid = threadIdx.x;
  int m0 = blockIdx.x * BM, n0 = blockIdx.y * BN;
  int lm = tid >> 2;
  int lk4 = (tid & 3) * 4;
  int bn_ = tid & 63;
  int bkq = (tid >> 6) * 4;
  int tm = (tid >> 4) * 4, tn = (tid & 15) * 4;
  float acc[4][4] = {};
  for (int k0 = 0; k0 < K; k0 += BK) {
    float4 av4 = make_float4(0.f, 0.f, 0.f, 0.f);
    if (m0 + lm < M) av4 = *(const float4*)(A + (size_t)(m0 + lm) * K + k0 + lk4);
    As[lk4 + 0][lm] = av4.x;
    As[lk4 + 1][lm] = av4.y;
    As[lk4 + 2][lm] = av4.z;
    As[lk4 + 3][lm] = av4.w;
#pragma unroll
    for (int c = 0; c < 4; ++c) {
      int k = k0 + bkq + c;
      Bs[bkq + c][bn_] = (k < K) ? B[(size_t)k * N + n0 + bn_] : 0.f;
    }
    __syncthreads();
#pragma unroll
    for (int kk = 0; kk < BK; ++kk) {
      float av[4], bv[4];
#pragma unroll
      for (int i = 0; i < 4; ++i) { av[i] = As[kk][tm + i]; bv[i] = Bs[kk][tn + i]; }
#pragma unroll
      for (int i = 0; i < 4; ++i)
#pragma unroll
        for (int jj = 0; jj < 4; ++jj) acc[i][jj] = fmaf(av[i], bv[jj], acc[i][jj]);
    }
    __syncthreads();
  }
#pragma unroll
  for (int i = 0; i < 4; ++i) {
    int m = m0 + tm + i;
    if (m < M) {
      float4 v = make_float4(acc[i][0], acc[i][1], acc[i][2], acc[i][3]);
      *(float4*)(C + (size_t)m * N + n0 + tn) = v;
    }
  }
}

// ---------------- row dots for GAT2 attention scalars ----------------

__global__ __launch_bounds__(256) void k_rowdots(const float* __restrict__ xw2, const float* __restrict__ as2,
                                                 const float* __restrict__ ad2, float* __restrict__ a2s,
                                                 float* __restrict__ a2d) {
  __shared__ float r1[256], r2[256];
  int n = blockIdx.x, j = threadIdx.x;
  float v = xw2[(size_t)n * 256 + j];
  r1[j] = v * as2[j];
  r2[j] = v * ad2[j];
  __syncthreads();
  for (int s = 128; s > 0; s >>= 1) {
    if (j < s) { r1[j] += r1[j + s]; r2[j] += r2[j + s]; }
    __syncthreads();
  }
  if (j == 0) { a2s[n] = r1[0]; a2d[n] = r2[0]; }
}

__global__ __launch_bounds__(256) void k_gat2_scatter(const float* __restrict__ a2s, const float* __restrict__ a2d,
                                                      const unsigned* __restrict__ m2, const int* __restrict__ src,
                                                      const int* __restrict__ dst, const float* __restrict__ xw2,
                                                      float* __restrict__ z2, float* __restrict__ acc2, int E, int N) {
  int j = threadIdx.x;
  for (int i = blockIdx.x; i < E + N; i += gridDim.x) {
    int s, d;
    if (i < E) { s = src[i]; d = dst[i]; } else { s = i - E; d = s; }
    float e = lrelu(a2s[s] + a2d[d]);
    float p = __expf(e - fdec(m2[d]));
    if (j == 0) atomicAdd(&z2[d], p);
    atomicAdd(&acc2[(size_t)d * 256 + j], p * xw2[(size_t)s * 256 + j]);
  }
}

__global__ __launch_bounds__(256) void k_gat2_node(float* __restrict__ acc2, const float* __restrict__ z2,
                                                   const float* __restrict__ b2, const float* __restrict__ gamma,
                                                   const float* __restrict__ beta, const float* __restrict__ mean,
                                                   const float* __restrict__ var) {
  int n = blockIdx.x, j = threadIdx.x;
  size_t idx = (size_t)n * 256 + j;
  float v = acc2[idx] / z2[n] + b2[j];
  v = (v - mean[j]) * rsqrtf(var[j] + BN_EPS) * gamma[j] + beta[j];
  acc2[idx] = fmaxf(v, 0.f);
}

// ---------------- fused pipelined GRU ----------------
// Roles (one grid, NBLK=64 blocks, all co-resident on 256 CUs):
//   block 0            : layer-0 scan; waits done0[c]==NW0; publishes prog0=c+1
//   block 1            : layer-1 scan; waits done1[c]==NW1
//   blocks 2..2+NW0-1  : gi0 workers (wait NOTHING) -> write gi slot c, bump done0[c]
//   rest (NW1)         : gi1 workers; wait prog0>=c+1 -> overwrite gi slot c, bump done1[c]
// DAG: gi0 -> scan0 -> gi1 -> scan1; no cycles, no deadlock.
//
// Round-15: AGPR residence (round-13, which achieved zero scratch) with the
// SCHEDULE repaired. HW fact: 384 KB of f16 weights can never fit the 256 KB
// VGPR half of the file at 8-wave residency; the unified AGPR half is the
// only on-CU storage for the overflow. Round-13's +35% came from 128
// separate volatile accvgpr_reads each immediately feeding a pkfma. Fix:
// (a) batch 4 reads into ONE volatile asm (32 blocks/step), (b) software-
// pipeline 1 deep — read iter i+1's weights into alternate temps before
// iter i's 6 pkfma, letting the scheduler fill read latency with math.
// Math bit-identical to rounds 11/13 (absmax 0.00048828125).

union H8U { h8v v; h2v h[4]; };

#define RPT32(M) M(0) M(1) M(2) M(3) M(4) M(5) M(6) M(7) M(8) M(9) M(10) M(11) M(12) M(13) M(14) M(15) \
                 M(16) M(17) M(18) M(19) M(20) M(21) M(22) M(23) M(24) M(25) M(26) M(27) M(28) M(29) M(30) M(31)

// wra/wza stay VGPR (64 regs, KEEPW'd); wna + wrb/wzb/wnb live in AGPRs (128).
#define DECLW(i) h2v wra##i, wza##i; int ana##i, arb##i, azb##i, anb##i;
#define AWRITE(dst, v_) { int b_ = __builtin_bit_cast(int, v_); \
  asm volatile("v_accvgpr_write_b32 %0, %1" : "=a"(dst) : "v"(b_)); }
#define LOADW(i) { float2 t_; h2v v_; \
  t_ = pra[i]; v_.x = (_Float16)t_.x; v_.y = (_Float16)t_.y; wra##i = v_; \
  t_ = pza[i]; v_.x = (_Float16)t_.x; v_.y = (_Float16)t_.y; wza##i = v_; \
  t_ = pna[i]; v_.x = (_Float16)t_.x; v_.y = (_Float16)t_.y; AWRITE(ana##i, v_) \
  t_ = prb[i]; v_.x = (_Float16)t_.x; v_.y = (_Float16)t_.y; AWRITE(arb##i, v_) \
  t_ = pzb[i]; v_.x = (_Float16)t_.x; v_.y = (_Float16)t_.y; AWRITE(azb##i, v_) \
  t_ = pnb[i]; v_.x = (_Float16)t_.x; v_.y = (_Float16)t_.y; AWRITE(anb##i, v_) }
#define KEEPW(i) asm volatile("" : "+v"(wra##i), "+v"(wza##i));

// Batched 4-way AGPR read: ONE volatile asm per dot-iteration.
#define AREAD4(d0, d1, d2, d3, i) { int t0_, t1_, t2_, t3_; \
  asm volatile("v_accvgpr_read_b32 %0, %4\n\t" \
               "v_accvgpr_read_b32 %1, %5\n\t" \
               "v_accvgpr_read_b32 %2, %6\n\t" \
               "v_accvgpr_read_b32 %3, %7" \
               : "=v"(t0_), "=v"(t1_), "=v"(t2_), "=v"(t3_) \
               : "a"(ana##i), "a"(arb##i), "a"(azb##i), "a"(anb##i)); \
  d0 = __builtin_bit_cast(h2v, t0_); d1 = __builtin_bit_cast(h2v, t1_); \
  d2 = __builtin_bit_cast(h2v, t2_); d3 = __builtin_bit_cast(h2v, t3_); }

// 6 pkfma for iteration i using already-loaded temps (n_,r_,z_,b_).
#define DOTC(i, XE, n_, r_, z_, b_) { h2v xe_ = (XE); \
  aRA = pkfma(wra##i, xe_, aRA); aZA = pkfma(wza##i, xe_, aZA); aNA = pkfma(n_, xe_, aNA); \
  aRB = pkfma(r_, xe_, aRB); aZB = pkfma(z_, xe_, aZB); aNB = pkfma(b_, xe_, aNB); }

// Pipelined pair: read (ia+1) into set1, compute ia with set0; read (ia+2)
// into set0, compute ia+1 with set1.
#define P2(ia, ib, in1, in2, XEa, XEb) \
  AREAD4(n1_, r1_, z1_, b1_, in1) \
  DOTC(ia, XEa, n0_, r0_, z0_, b0_) \
  AREAD4(n0_, r0_, z0_, b0_, in2) \
  DOTC(ib, XEb, n1_, r1_, z1_, b1_)

template <int ROLE>
__device__ __forceinline__ void gru_scan_dev(_Float16* __restrict__ hb,   // LDS, 2*288 f16
                                             const float* __restrict__ Whh, const float* __restrict__ bhh,
                                             const _Float16* __restrict__ giT, _Float16* __restrict__ gout,
                                             int T, int* __restrict__ prog, int* __restrict__ done, int ndone) {
  int j = threadIdx.x;   // 0..511
  int q = j & 3;         // K-quarter
  int du = j >> 2;       // unit-pair 0..127
  int uA = du, uB = du + 128;
  int k0 = q * 64;       // this thread's K range: [k0, k0+64)
  RPT32(DECLW)
  {
    const float2* pra = (const float2*)(Whh + (size_t)uA * 256 + k0);
    const float2* pza = (const float2*)(Whh + (size_t)(uA + 256) * 256 + k0);
    const float2* pna = (const float2*)(Whh + (size_t)(uA + 512) * 256 + k0);
    const float2* prb = (const float2*)(Whh + (size_t)uB * 256 + k0);
    const float2* pzb = (const float2*)(Whh + (size_t)(uB + 256) * 256 + k0);
    const float2* pnb = (const float2*)(Whh + (size_t)(uB + 512) * 256 + k0);
    RPT32(LOADW)
  }
  RPT32(KEEPW)
  int uus = du + ((q & 1) << 7);   // unit this lane finalizes (q2/3 mirror q0/1)
  float bhr = bhh[uus], bhz = bhh[uus + 256], bhn = bhh[uus + 512];
  // hb layout: 2 phases x (4 regions x 72 f16). Unit u at (u>>6)*72+(u&63);
  // pads 64..71. Region base q*144 B -> disjoint bank quads for broadcasts.
  for (int i = j; i < 2 * 288; i += 512) hb[i] = (_Float16)0.f;
  __syncthreads();
  int slot = (uus >> 6) * 72 + (uus & 63);
  float h = 0.f;
  const _Float16* pR = giT + (size_t)uus * T;
  size_t oZ = (size_t)256 * T, oN = (size_t)512 * T;
  _Float16* gorow = gout + (size_t)uus * T;
  int NC = (T + GCHUNK - 1) / GCHUNK;
  for (int c = 0; c < NC; ++c) {
    int cb = c * GCHUNK;
    int ce = min(cb + GCHUNK, T);
    if (j == 0) {
      while (__hip_atomic_load(&done[c], __ATOMIC_RELAXED, __HIP_MEMORY_SCOPE_AGENT) < ndone)
        __builtin_amdgcn_s_sleep(32);
    }
    __syncthreads();
    __threadfence();   // acquire: invalidate caches before reading the chunk
    h4v cR = *(const h4v*)(pR + cb);
    h4v cZ = *(const h4v*)(pR + oZ + cb);
    h4v cN = *(const h4v*)(pR + oN + cb);
    for (int t0 = cb; t0 < ce; t0 += 4) {
      h4v nR = cR, nZ = cZ, nN = cN;
      if (t0 + 4 < ce) {   // prefetch confined to chunk
        nR = *(const h4v*)(pR + t0 + 4);
        nZ = *(const h4v*)(pR + oZ + t0 + 4);
        nN = *(const h4v*)(pR + oN + t0 + 4);
      }
      h4v sb;
#pragma unroll
      for (int u = 0; u < 4; ++u) {
        int t = t0 + u;
        const h8v* hp8 = (const h8v*)&hb[(t & 1) * 288 + q * 72];
        h2v aRA = {}, aZA = {}, aNA = {}, aRB = {}, aZB = {}, aNB = {};
        h2v n0_, r0_, z0_, b0_, n1_, r1_, z1_, b1_;
        H8U xa[4];
        xa[0].v = hp8[0]; xa[1].v = hp8[1]; xa[2].v = hp8[2]; xa[3].v = hp8[3];
        AREAD4(n0_, r0_, z0_, b0_, 0)
        P2(0, 1, 1, 2, xa[0].h[0], xa[0].h[1])
        P2(2, 3, 3, 4, xa[0].h[2], xa[0].h[3])
        P2(4, 5, 5, 6, xa[1].h[0], xa[1].h[1])
        P2(6, 7, 7, 8, xa[1].h[2], xa[1].h[3])
        P2(8, 9, 9, 10, xa[2].h[0], xa[2].h[1])
        P2(10, 11, 11, 12, xa[2].h[2], xa[2].h[3])
        P2(12, 13, 13, 14, xa[3].h[0], xa[3].h[1])
        P2(14, 15, 15, 16, xa[3].h[2], xa[3].h[3])
        xa[0].v = hp8[4]; xa[1].v = hp8[5]; xa[2].v = hp8[6]; xa[3].v = hp8[7];
        P2(16, 17, 17, 18, xa[0].h[0], xa[0].h[1])
        P2(18, 19, 19, 20, xa[0].h[2], xa[0].h[3])
        P2(20, 21, 21, 22, xa[1].h[0], xa[1].h[1])
        P2(22, 23, 23, 24, xa[1].h[2], xa[1].h[3])
        P2(24, 25, 25, 26, xa[2].h[0], xa[2].h[1])
        P2(26, 27, 27, 28, xa[2].h[2], xa[2].h[3])
        P2(28, 29, 29, 30, xa[3].h[0], xa[3].h[1])
        AREAD4(n1_, r1_, z1_, b1_, 31)
        DOTC(30, xa[3].h[2], n0_, r0_, z0_, b0_)
        DOTC(31, xa[3].h[3], n1_, r1_, z1_, b1_)
        float arA = (float)aRA.x + (float)aRA.y;
        float azA = (float)aZA.x + (float)aZA.y;
        float anA = (float)aNA.x + (float)aNA.y;
        float arB = (float)aRB.x + (float)aRB.y;
        float azB = (float)aZB.x + (float)aZB.y;
        float anB = (float)aNB.x + (float)aNB.y;
        // 4-lane butterfly over K-quarters (VALU/DPP; all lanes get full sums)
        arA += dpp_xor1(arA); arA += dpp_xor2(arA);
        azA += dpp_xor1(azA); azA += dpp_xor2(azA);
        anA += dpp_xor1(anA); anA += dpp_xor2(anA);
        arB += dpp_xor1(arB); arB += dpp_xor2(arB);
        azB += dpp_xor1(azB); azB += dpp_xor2(azB);
        anB += dpp_xor1(anB); anB += dpp_xor2(anB);
        float ar = ((q & 1) ? arB : arA) + bhr;
        float az = ((q & 1) ? azB : azA) + bhz;
        float an = ((q & 1) ? anB : anA) + bhn;
        float gir = (float)cR[u], giz = (float)cZ[u], gin = (float)cN[u];
        float r = sigf(gir + ar);
        float zt = sigf(giz + az);
        float nn = tanhfast(gin + r * an);
        h = (1.f - zt) * nn + zt * h;
        sb[u] = (_Float16)h;
        if (q < 2) hb[((t & 1) ^ 1) * 288 + slot] = (_Float16)h;
        step_barrier();   // lgkm-only: gi prefetch/gout stores stay in flight
      }
      if (q < 2) *(h4v*)(gorow + t0) = sb;
      cR = nR; cZ = nZ; cN = nN;
    }
    if (ROLE == 0) {
      __threadfence();   // release: drain this thread's g0 stores + L2 wb
      __syncthreads();
      if (j == 0) __hip_atomic_store(&prog[0], c + 1, __ATOMIC_RELAXED, __HIP_MEMORY_SCOPE_AGENT);
    }
  }
}

// gi0 worker: gi0[:,m] = [h2[src[m]], h2[dst[m]], ea[m]] @ Wih0^T + bih0  (K=515)
// As: 16x64 floats (stride 64), Bs: 16x66 floats (stride 66), carved from pool.
__device__ __forceinline__ void gi0_worker(float* __restrict__ As, float* __restrict__ Bs,
                                           const float* __restrict__ h2, const int* __restrict__ src,
                                           const int* __restrict__ dst, const float* __restrict__ ea,
                                           const float* __restrict__ W, const float* __restrict__ bias,
                                           _Float16* __restrict__ giT, int T, int w,
                                           int* __restrict__ done, int NC) {
  int tid = threadIdx.x;
  int lk = tid >> 5, lm2 = (tid & 31) * 2;   // A load: [k][m], 2 m's per thread
  int bn = tid >> 3, bk2 = (tid & 7) * 2;    // B load: [k][n], 2 k's per thread
  int tm = (tid >> 4) * 2, tn = (tid & 15) * 4;
  for (int c = 0; c < NC; ++c) {
    int cb = c * GCHUNK;
    int clen = min(GCHUNK, T - cb);
    int mt = (clen + 63) >> 6;
    int ntile = mt * 12;   // 768/64 feature tiles
    for (int tile = w; tile < ntile; tile += NW0) {
      int m0 = cb + (tile % mt) * 64;
      int n0 = (tile / mt) * 64;
      int mA0 = m0 + lm2, mA1 = mA0 + 1;
      int s0 = (mA0 < T) ? src[mA0] : 0, d0 = (mA0 < T) ? dst[mA0] : 0;
      int s1 = (mA1 < T) ? src[mA1] : 0, d1 = (mA1 < T) ? dst[mA1] : 0;
      float acc[2][4] = {};
      for (int k0 = 0; k0 < 515; k0 += 16) {
        int k = k0 + lk;
        float a0, a1;
        if (k < 256) {
          a0 = h2[(size_t)s0 * 256 + k];
          a1 = h2[(size_t)s1 * 256 + k];
        } else if (k < 512) {
          a0 = h2[(size_t)d0 * 256 + (k - 256)];
          a1 = h2[(size_t)d1 * 256 + (k - 256)];
        } else {
          a0 = (k < 515 && mA0 < T) ? ea[(size_t)mA0 * 3 + (k - 512)] : 0.f;
          a1 = (k < 515 && mA1 < T) ? ea[(size_t)mA1 * 3 + (k - 512)] : 0.f;
        }
        As[lk * 64 + lm2] = a0;
        As[lk * 64 + lm2 + 1] = a1;
        Bs[bk2 * 66 + bn] = (k0 + bk2 < 515) ? W[(size_t)(n0 + bn) * 515 + k0 + bk2] : 0.f;
        Bs[(bk2 + 1) * 66 + bn] = (k0 + bk2 + 1 < 515) ? W[(size_t)(n0 + bn) * 515 + k0 + bk2 + 1] : 0.f;
        __syncthreads();
#pragma unroll
        for (int kk = 0; kk < 16; ++kk) {
          float a0v = As[kk * 64 + tm], a1v = As[kk * 64 + tm + 1];
          float b0 = Bs[kk * 66 + tn], b1 = Bs[kk * 66 + tn + 1];
          float b2v = Bs[kk * 66 + tn + 2], b3 = Bs[kk * 66 + tn + 3];
          acc[0][0] = fmaf(a0v, b0, acc[0][0]);
          acc[0][1] = fmaf(a0v, b1, acc[0][1]);
          acc[0][2] = fmaf(a0v, b2v, acc[0][2]);
          acc[0][3] = fmaf(a0v, b3, acc[0][3]);
          acc[1][0] = fmaf(a1v, b0, acc[1][0]);
          acc[1][1] = fmaf(a1v, b1, acc[1][1]);
          acc[1][2] = fmaf(a1v, b2v, acc[1][2]);
          acc[1][3] = fmaf(a1v, b3, acc[1][3]);
        }
        __syncthreads();
      }
#pragma unroll
      for (int i = 0; i < 2; ++i) {
        int m = m0 + tm + i;
        if (m < T) {
#pragma unroll
          for (int qq = 0; qq < 4; ++qq)
            giT[(size_t)(n0 + tn + qq) * T + m] = (_Float16)(acc[i][qq] + bias[n0 + tn + qq]);
        }
      }
    }
    __threadfence();   // release: flush gi0 chunk stores
    __syncthreads();
    if (tid == 0) __hip_atomic_fetch_add(&done[c], 1, __ATOMIC_RELAXED, __HIP_MEMORY_SCOPE_AGENT);
  }
}

// gi1 worker: overwrites gi slot c (gi0 consumed) with g0_chunk @ Wih1^T + bih1.
__device__ __forceinline__ void gi1_worker(float* __restrict__ As, float* __restrict__ Bs,
                                           const _Float16* __restrict__ g0, const float* __restrict__ Wih1,
                                           const float* __restrict__ bih1, _Float16* __restrict__ giT,
                                           int T, int w, int* __restrict__ prog, int* __restrict__ done, int NC) {
  int tid = threadIdx.x;
  int lk = tid >> 5, lm = (tid & 31) * 2;
  int bk = (tid & 7) * 2, bn = tid >> 3;
  int tm = (tid >> 4) * 2, tn = (tid & 15) * 4;
  for (int c = 0; c < NC; ++c) {
    if (tid == 0) {
      while (__hip_atomic_load(&prog[0], __ATOMIC_RELAXED, __HIP_MEMORY_SCOPE_AGENT) < c + 1)
        __builtin_amdgcn_s_sleep(32);
    }
    __syncthreads();
    __threadfence();   // acquire: g0 chunk may be stale in this XCD's L2
    int cb = c * GCHUNK;
    int clen = min(GCHUNK, T - cb);
    int mt = (clen + 63) >> 6;
    int ntile = mt * 12;
    for (int tile = w; tile < ntile; tile += NW1) {
      int m0 = cb + (tile % mt) * 64;
      int n0 = (tile / mt) * 64;
      float acc[2][4] = {};
      for (int k0 = 0; k0 < 256; k0 += 16) {
        int m = m0 + lm;
        float ax = 0.f, ay = 0.f;
        if (m + 1 < T) {
          h2v hv = *(const h2v*)(g0 + (size_t)(k0 + lk) * T + m);
          ax = (float)hv.x; ay = (float)hv.y;
        } else if (m < T) {
          ax = (float)g0[(size_t)(k0 + lk) * T + m];
        }
        As[lk * 64 + lm] = ax;
        As[lk * 64 + lm + 1] = ay;
        float2 bv2 = *(const float2*)(Wih1 + (size_t)(n0 + bn) * 256 + k0 + bk);
        Bs[bk * 66 + bn] = bv2.x;
        Bs[(bk + 1) * 66 + bn] = bv2.y;
        __syncthreads();
#pragma unroll
        for (int kk = 0; kk < 16; ++kk) {
          float a0 = As[kk * 64 + tm], a1 = As[kk * 64 + tm + 1];
          float b0 = Bs[kk * 66 + tn], b1 = Bs[kk * 66 + tn + 1];
          float b2v = Bs[kk * 66 + tn + 2], b3 = Bs[kk * 66 + tn + 3];
          acc[0][0] = fmaf(a0, b0, acc[0][0]);
          acc[0][1] = fmaf(a0, b1, acc[0][1]);
          acc[0][2] = fmaf(a0, b2v, acc[0][2]);
          acc[0][3] = fmaf(a0, b3, acc[0][3]);
          acc[1][0] = fmaf(a1, b0, acc[1][0]);
          acc[1][1] = fmaf(a1, b1, acc[1][1]);
          acc[1][2] = fmaf(a1, b2v, acc[1][2]);
          acc[1][3] = fmaf(a1, b3, acc[1][3]);
        }
        __syncthreads();
      }
#pragma unroll
      for (int i = 0; i < 2; ++i) {
        int m = m0 + tm + i;
        if (m < T) {
#pragma unroll
          for (int qq = 0; qq < 4; ++qq)
            giT[(size_t)(n0 + tn + qq) * T + m] = (_Float16)(acc[i][qq] + bih1[n0 + tn + qq]);
        }
      }
    }
    __threadfence();   // release: flush gi1 chunk stores
    __syncthreads();
    if (tid == 0) __hip_atomic_fetch_add(&done[c], 1, __ATOMIC_RELAXED, __HIP_MEMORY_SCOPE_AGENT);
  }
}

// 96 KB pool -> HW max 1 block/CU (validated round-11). Weights split
// VGPR(64 h2v)+AGPR(128 h2v) = full unified-file residence (round-13),
// with batched+pipelined accvgpr reads to fix round-13's schedule cost.
__global__ __attribute__((amdgpu_flat_work_group_size(512, 512), amdgpu_waves_per_eu(2, 2)))
void k_fused_gru(const float* __restrict__ Whh0, const float* __restrict__ bhh0,
                 const float* __restrict__ Whh1, const float* __restrict__ bhh1,
                 const float* __restrict__ h2, const int* __restrict__ src,
                 const int* __restrict__ dst, const float* __restrict__ ea,
                 const float* __restrict__ Wih0, const float* __restrict__ bih0,
                 const float* __restrict__ Wih1, const float* __restrict__ bih1,
                 _Float16* __restrict__ gi, _Float16* __restrict__ g0,
                 _Float16* __restrict__ g1, int T, int* __restrict__ flags,
                 int NC) {
  __shared__ __align__(16) char lds_pool[LDS_POOL_BYTES];
  int b = blockIdx.x;
  int* done0 = flags + 8;
  int* done1 = flags + 8 + NC;
  if (b == 0)
    gru_scan_dev<0>((_Float16*)lds_pool, Whh0, bhh0, gi, g0, T, flags, done0, NW0);
  else if (b == 1)
    gru_scan_dev<1>((_Float16*)lds_pool, Whh1, bhh1, gi, g1, T, flags, done1, NW1);
  else if (b < 2 + NW0)
    gi0_worker((float*)lds_pool, (float*)(lds_pool + 16 * 64 * 4),
               h2, src, dst, ea, Wih0, bih0, gi, T, b - 2, done0, NC);
  else
    gi1_worker((float*)lds_pool, (float*)(lds_pool + 16 * 64 * 4),
               g0, Wih1, bih1, gi, T, b - 2 - NW0, flags, done1, NC);
}

// ---------------- final MLP: out[t] = Wlin2 . relu(Wlin1 . g1_t + blin1) + blin2 ----------------

__global__ __launch_bounds__(128) void k_final(const _Float16* __restrict__ g1T, const float* __restrict__ Wlin1,
                                               const float* __restrict__ blin1, const float* __restrict__ Wlin2,
                                               const float* __restrict__ blin2, float* __restrict__ out, int E) {
  int j = threadIdx.x;  // 0..127
  float w[256];
#pragma unroll
  for (int k = 0; k < 256; ++k) w[k] = Wlin1[(size_t)j * 256 + k];
  float bj = blin1[j], w2j = Wlin2[j], b2v = blin2[0];
  __shared__ float gsf[256];
  __shared__ float red[128];
  for (int t = blockIdx.x; t < E; t += gridDim.x) {
    gsf[j] = (float)g1T[(size_t)j * E + t];
    gsf[j + 128] = (float)g1T[(size_t)(j + 128) * E + t];
    __syncthreads();
    float acc = 0.f;
#pragma unroll
    for (int k = 0; k < 256; ++k) acc = fmaf(w[k], gsf[k], acc);
    float v = fmaxf(acc + bj, 0.f) * w2j;
    red[j] = v;
    __syncthreads();
    for (int s = 64; s > 0; s >>= 1) {
      if (j < s) red[j] += red[j + s];
      __syncthreads();
    }
    if (j == 0) out[t] = red[0] + b2v;
    __syncthreads();
  }
}

// ---------------- launch ----------------

extern "C" void kernel_launch(void* const* d_in, const int* in_sizes, int n_in,
                              void* d_out, int out_size, void* d_ws, size_t ws_size,
                              hipStream_t stream) {
  (void)n_in; (void)out_size; (void)ws_size;
  const float* x = (const float*)d_in[0];
  const int* ei = (const int*)d_in[1];
  const float* ea = (const float*)d_in[2];
  const float* W1 = (const float*)d_in[3];
  const float* as1 = (const float*)d_in[4];
  const float* ad1 = (const float*)d_in[5];
  const float* b1 = (const float*)d_in[6];
  const float* gamma1 = (const float*)d_in[7];
  const float* beta1 = (const float*)d_in[8];
  const float* mean1 = (const float*)d_in[9];
  const float* var1 = (const float*)d_in[10];
  const float* W2 = (const float*)d_in[11];
  const float* as2 = (const float*)d_in[12];
  const float* ad2 = (const float*)d_in[13];
  const float* b2 = (const float*)d_in[14];
  const float* gamma2 = (const float*)d_in[15];
  const float* beta2 = (const float*)d_in[16];
  const float* mean2 = (const float*)d_in[17];
  const float* var2 = (const float*)d_in[18];
  const float* Wih0 = (const float*)d_in[19];
  const float* Whh0 = (const float*)d_in[20];
  const float* bih0 = (const float*)d_in[21];
  const float* bhh0 = (const float*)d_in[22];
  const float* Wih1 = (const float*)d_in[23];
  const float* Whh1 = (const float*)d_in[24];
  const float* bih1 = (const float*)d_in[25];
  const float* bhh1 = (const float*)d_in[26];
  const float* Wlin1 = (const float*)d_in[27];
  const float* blin1 = (const float*)d_in[28];
  const float* Wlin2 = (const float*)d_in[29];
  const float* blin2 = (const float*)d_in[30];

  int N = in_sizes[0];
  int E = in_sizes[1] / 2;
  const int* src = ei;
  const int* dst = ei + E;

  char* wsp = (char*)d_ws;
  size_t off = 0;
  auto carve = [&](size_t bytes) -> void* {
    void* p = wsp + off;
    off = (off + bytes + 255) & ~(size_t)255;
    return p;
  };
  float* c12 = (float*)carve(2 * sizeof(float));
  float* a1s = (float*)carve((size_t)N * 4);
  float* a1d = (float*)carve((size_t)N * 4);
  unsigned* m1 = (unsigned*)carve((size_t)N * 4);
  float* z1 = (float*)carve((size_t)N * 4);
  float* uacc = (float*)carve((size_t)N * 4);
  float* h1 = (float*)carve((size_t)N * 256 * 4);
  float* xw2 = (float*)carve((size_t)N * 256 * 4);
  float* a2s = (float*)carve((size_t)N * 4);
  float* a2d = (float*)carve((size_t)N * 4);
  unsigned* m2 = (unsigned*)carve((size_t)N * 4);
  float* z2 = (float*)carve((size_t)N * 4);
  float* acc2 = (float*)carve((size_t)N * 256 * 4);          // becomes h2 in-place
  _Float16* gi = (_Float16*)carve((size_t)E * 768 * 2);      // feature-major [768, E]; gi0 then gi1 in place, chunkwise
  _Float16* g0 = (_Float16*)carve((size_t)E * 256 * 2);      // feature-major [256, E]
  _Float16* g1 = (_Float16*)carve((size_t)E * 256 * 2);      // feature-major [256, E]
  int NCh = (E + GCHUNK - 1) / GCHUNK;
  int flagN = 8 + 2 * NCh;                                   // [0]=prog0, done0[NC], done1[NC]
  int* flags = (int*)carve((size_t)flagN * 4);

  hipMemsetAsync(m1, 0, (size_t)N * 4, stream);
  hipMemsetAsync(z1, 0, (size_t)N * 4, stream);
  hipMemsetAsync(uacc, 0, (size_t)N * 4, stream);
  hipMemsetAsync(m2, 0, (size_t)N * 4, stream);
  hipMemsetAsync(z2, 0, (size_t)N * 4, stream);
  hipMemsetAsync(acc2, 0, (size_t)N * 256 * 4, stream);
  hipMemsetAsync(flags, 0, (size_t)flagN * 4, stream);

  int eb = (E + N + 255) / 256;

  k_prep_c<<<1, 256, 0, stream>>>(W1, as1, ad1, c12);
  k_a1<<<(N + 255) / 256, 256, 0, stream>>>(x, c12, a1s, a1d, N);
  k_edge_max<<<eb, 256, 0, stream>>>(a1s, a1d, m1, src, dst, E, N);
  k_gat1_edge_sum<<<eb, 256, 0, stream>>>(a1s, a1d, m1, src, dst, x, z1, uacc, E, N);
  k_gat1_node<<<N, 256, 0, stream>>>(uacc, z1, W1, b1, gamma1, beta1, mean1, var1, h1);

  dim3 gx((N + BM - 1) / BM, 256 / BN);
  k_gemm_f32<<<gx, 256, 0, stream>>>(h1, W2, xw2, N, 256, 256);
  k_rowdots<<<N, 256, 0, stream>>>(xw2, as2, ad2, a2s, a2d);
  k_edge_max<<<eb, 256, 0, stream>>>(a2s, a2d, m2, src, dst, E, N);
  k_gat2_scatter<<<4096, 256, 0, stream>>>(a2s, a2d, m2, src, dst, xw2, z2, acc2, E, N);
  k_gat2_node<<<N, 256, 0, stream>>>(acc2, z2, b2, gamma2, beta2, mean2, var2);

  // fused pipelined GRU: gi0 workers feed scan0; gi1 workers feed scan1.
  k_fused_gru<<<NBLK, 512, 0, stream>>>(Whh0, bhh0, Whh1, bhh1, acc2, src, dst, ea,
                                        Wih0, bih0, Wih1, bih1, gi, g0, g1, E, flags, NCh);

  k_final<<<1024, 128, 0, stream>>>(g1, Wlin1, blin1, Wlin2, blin2, (float*)d_out, E);
}

// Round 17
// 78568.213 us; speedup vs baseline: 1.4246x; 1.4246x over previous
//
#include <hip/hip_runtime.h>
#include <cstdint>
#include <cstddef>

typedef _Float16 h2v __attribute__((ext_vector_type(2)));
typedef _Float16 h4v __attribute__((ext_vector_type(4)));
typedef _Float16 h8v __attribute__((ext_vector_type(8)));
typedef float f4v __attribute__((ext_vector_type(4)));

#define NEG_SLOPE 0.2f
#define BN_EPS 1e-5f
#define BM 64
#define BN 64
#define BK 16
#define GCHUNK 1024   // GRU pipeline chunk (steps); must be multiple of 8
#define NW0 40        // gi0 GEMM workers (h2-gather @ Wih0^T, K=515)
#define NW1 22        // gi1 GEMM workers (g0 @ Wih1^T, K=256)
#define NBLK (2 + NW0 + NW1)
#define LDS_POOL_BYTES 98304   // 96 KB: HW max 1 block/CU (validated round-11)

__device__ __forceinline__ float lrelu(float x) { return x > 0.f ? x : NEG_SLOPE * x; }

__device__ __forceinline__ unsigned fenc(float f) {
  unsigned b = __float_as_uint(f);
  return (b & 0x80000000u) ? ~b : (b | 0x80000000u);
}
__device__ __forceinline__ float fdec(unsigned u) {
  return (u & 0x80000000u) ? __uint_as_float(u & 0x7fffffffu) : __uint_as_float(~u);
}

__device__ __forceinline__ float sigf(float x) { return 1.f / (1.f + __expf(-x)); }
__device__ __forceinline__ float tanhfast(float x) {
  x = fminf(fmaxf(x, -20.f), 20.f);
  float e = __expf(2.f * x);
  return (e - 1.f) / (e + 1.f);
}

// Per-step barrier for the GRU scan: only LDS ordering is required for the
// h hand-off (LDS is CU-local). __syncthreads() would drain vmcnt(0) too,
// serializing the gi prefetch / gout store latency into the recurrence.
__device__ __forceinline__ void step_barrier() {
  __builtin_amdgcn_sched_barrier(0);
  asm volatile("s_waitcnt lgkmcnt(0)" ::: "memory");
  __builtin_amdgcn_s_barrier();
  __builtin_amdgcn_sched_barrier(0);
}

// ---------------- GAT layer 1 (rank-1 collapse) ----------------

__global__ __launch_bounds__(256) void k_prep_c(const float* __restrict__ W1,
                                                const float* __restrict__ as1,
                                                const float* __restrict__ ad1,
                                                float* __restrict__ c12) {
  __shared__ float r1[256], r2[256];
  int j = threadIdx.x;
  float wv = W1[j];
  r1[j] = wv * as1[j];
  r2[j] = wv * ad1[j];
  __syncthreads();
  for (int s = 128; s > 0; s >>= 1) {
    if (j < s) { r1[j] += r1[j + s]; r2[j] += r2[j + s]; }
    __syncthreads();
  }
  if (j == 0) { c12[0] = r1[0]; c12[1] = r2[0]; }
}

__global__ __launch_bounds__(256) void k_a1(const float* __restrict__ x, const float* __restrict__ c12,
                                            float* __restrict__ a1s, float* __restrict__ a1d, int N) {
  int i = blockIdx.x * 256 + threadIdx.x;
  if (i < N) {
    float xv = x[i];
    a1s[i] = c12[0] * xv;
    a1d[i] = c12[1] * xv;
  }
}

__global__ __launch_bounds__(256) void k_edge_max(const float* __restrict__ as_, const float* __restrict__ ad_,
                                                  unsigned* __restrict__ menc, const int* __restrict__ src,
                                                  const int* __restrict__ dst, int E, int N) {
  int i = blockIdx.x * 256 + threadIdx.x;
  if (i >= E + N) return;
  int s, d;
  if (i < E) { s = src[i]; d = dst[i]; } else { s = i - E; d = s; }
  float e = lrelu(as_[s] + ad_[d]);
  atomicMax(&menc[d], fenc(e));
}

__global__ __launch_bounds__(256) void k_gat1_edge_sum(const float* __restrict__ as_, const float* __restrict__ ad_,
                                                       const unsigned* __restrict__ menc, const int* __restrict__ src,
                                                       const int* __restrict__ dst, const float* __restrict__ x,
                                                       float* __restrict__ z, float* __restrict__ uacc, int E, int N) {
  int i = blockIdx.x * 256 + threadIdx.x;
  if (i >= E + N) return;
  int s, d;
  if (i < E) { s = src[i]; d = dst[i]; } else { s = i - E; d = s; }
  float e = lrelu(as_[s] + ad_[d]);
  float p = __expf(e - fdec(menc[d]));
  atomicAdd(&z[d], p);
  atomicAdd(&uacc[d], p * x[s]);
}

__global__ __launch_bounds__(256) void k_gat1_node(const float* __restrict__ uacc, const float* __restrict__ z1,
                                                   const float* __restrict__ W1, const float* __restrict__ b1,
                                                   const float* __restrict__ gamma, const float* __restrict__ beta,
                                                   const float* __restrict__ mean, const float* __restrict__ var,
                                                   float* __restrict__ h1) {
  int n = blockIdx.x, j = threadIdx.x;
  float u = uacc[n] / z1[n];
  float v = u * W1[j] + b1[j];
  v = (v - mean[j]) * rsqrtf(var[j] + BN_EPS) * gamma[j] + beta[j];
  h1[(size_t)n * 256 + j] = fmaxf(v, 0.f);
}

// ---------------- generic fp32 tiled GEMM: C[M,N] = A[M,K] * B[K,N] ----------------

__global__ __launch_bounds__(256) void k_gemm_f32(const float* __restrict__ A, const float* __restrict__ B,
                                                  float* __restrict__ C, int M, int N, int K) {
  __shared__ float As[BK][BM];
  __shared__ float Bs[BK][BN];
  int tid = threadIdx.x;
  int m0 = blockIdx.x * BM, n0 = blockIdx.y * BN;
  int lm = tid >> 2;
  int lk4 = (tid & 3) * 4;
  int bn_ = tid & 63;
  int bkq = (tid >> 6) * 4;
  int tm = (tid >> 4) * 4, tn = (tid & 15) * 4;
  float acc[4][4] = {};
  for (int k0 = 0; k0 < K; k0 += BK) {
    float4 av4 = make_float4(0.f, 0.f, 0.f, 0.f);
    if (m0 + lm < M) av4 = *(const float4*)(A + (size_t)(m0 + lm) * K + k0 + lk4);
    As[lk4 + 0][lm] = av4.x;
    As[lk4 + 1][lm] = av4.y;
    As[lk4 + 2][lm] = av4.z;
    As[lk4 + 3][lm] = av4.w;
#pragma unroll
    for (int c = 0; c < 4; ++c) {
      int k = k0 + bkq + c;
      Bs[bkq + c][bn_] = (k < K) ? B[(size_t)k * N + n0 + bn_] : 0.f;
    }
    __syncthreads();
#pragma unroll
    for (int kk = 0; kk < BK; ++kk) {
      float av[4], bv[4];
#pragma unroll
      for (int i = 0; i < 4; ++i) { av[i] = As[kk][tm + i]; bv[i] = Bs[kk][tn + i]; }
#pragma unroll
      for (int i = 0; i < 4; ++i)
#pragma unroll
        for (int jj = 0; jj < 4; ++jj) acc[i][jj] = fmaf(av[i], bv[jj], acc[i][jj]);
    }
    __syncthreads();
  }
#pragma unroll
  for (int i = 0; i < 4; ++i) {
    int m = m0 + tm + i;
    if (m < M) {
      float4 v = make_float4(acc[i][0], acc[i][1], acc[i][2], acc[i][3]);
      *(float4*)(C + (size_t)m * N + n0 + tn) = v;
    }
  }
}

// ---------------- row dots for GAT2 attention scalars ----------------

__global__ __launch_bounds__(256) void k_rowdots(const float* __restrict__ xw2, const float* __restrict__ as2,
                                                 const float* __restrict__ ad2, float* __restrict__ a2s,
                                                 float* __restrict__ a2d) {
  __shared__ float r1[256], r2[256];
  int n = blockIdx.x, j = threadIdx.x;
  float v = xw2[(size_t)n * 256 + j];
  r1[j] = v * as2[j];
  r2[j] = v * ad2[j];
  __syncthreads();
  for (int s = 128; s > 0; s >>= 1) {
    if (j < s) { r1[j] += r1[j + s]; r2[j] += r2[j + s]; }
    __syncthreads();
  }
  if (j == 0) { a2s[n] = r1[0]; a2d[n] = r2[0]; }
}

__global__ __launch_bounds__(256) void k_gat2_scatter(const float* __restrict__ a2s, const float* __restrict__ a2d,
                                                      const unsigned* __restrict__ m2, const int* __restrict__ src,
                                                      const int* __restrict__ dst, const float* __restrict__ xw2,
                                                      float* __restrict__ z2, float* __restrict__ acc2, int E, int N) {
  int j = threadIdx.x;
  for (int i = blockIdx.x; i < E + N; i += gridDim.x) {
    int s, d;
    if (i < E) { s = src[i]; d = dst[i]; } else { s = i - E; d = s; }
    float e = lrelu(a2s[s] + a2d[d]);
    float p = __expf(e - fdec(m2[d]));
    if (j == 0) atomicAdd(&z2[d], p);
    atomicAdd(&acc2[(size_t)d * 256 + j], p * xw2[(size_t)s * 256 + j]);
  }
}

__global__ __launch_bounds__(256) void k_gat2_node(float* __restrict__ acc2, const float* __restrict__ z2,
                                                   const float* __restrict__ b2, const float* __restrict__ gamma,
                                                   const float* __restrict__ beta, const float* __restrict__ mean,
                                                   const float* __restrict__ var) {
  int n = blockIdx.x, j = threadIdx.x;
  size_t idx = (size_t)n * 256 + j;
  float v = acc2[idx] / z2[n] + b2[j];
  v = (v - mean[j]) * rsqrtf(var[j] + BN_EPS) * gamma[j] + beta[j];
  acc2[idx] = fmaxf(v, 0.f);
}

// ---------------- fused pipelined GRU ----------------
// Roles (one grid, NBLK=64 blocks, all co-resident on 256 CUs):
//   block 0            : layer-0 scan; waits done0[c]==NW0; publishes prog0=c+1
//   block 1            : layer-1 scan; waits done1[c]==NW1
//   blocks 2..2+NW0-1  : gi0 workers (wait NOTHING) -> write gi slot c, bump done0[c]
//   rest (NW1)         : gi1 workers; wait prog0>=c+1 -> overwrite gi slot c, bump done1[c]
// DAG: gi0 -> scan0 -> gi1 -> scan1; no cycles, no deadlock.
//
// Round-17: MFMA SCAN. Established facts: (a) VGPR residence of the 384 KB
// weight set is impossible at any block size (budget=65536/thr < need=
// 98304/thr); (b) AGPRs allocate (128+128=256/thr ran, rounds 13-15) but
// VALU cannot read them (round-16 assembler proof) and read-backs cost more
// than scratch; (c) MFMA is the ONLY class that consumes AGPRs directly.
// So the per-step GEMV gates=Whh*h runs on the matrix pipe:
//   48 tiles x 8 K-chunks of v_mfma_f32_16x16x32_f16 (48 MFMA/wave/step),
//   B-frags = weights (lane l: W[16t+(l&15)][32c+(l>>4)*8+e]), 32 frags in
//   AGPR ("a" constraint) + 16 in VGPR; A = h BROADCAST to all 16 rows
//   (row-mapping-proof; within-chunk k-permutations cancel by A/B layout
//   symmetry); D f32 (m89-verified col=lane&15) -> y in lanes 0-15.
// Epilogue per step: y -> LDS, barrier, threads j<256 gate-combine unit j,
// write h, barrier. Weight memory traffic per step: ZERO.

#define RPT48(M) M(0) M(1) M(2) M(3) M(4) M(5) M(6) M(7) M(8) M(9) M(10) M(11) M(12) M(13) M(14) M(15) \
                 M(16) M(17) M(18) M(19) M(20) M(21) M(22) M(23) M(24) M(25) M(26) M(27) M(28) M(29) M(30) M(31) \
                 M(32) M(33) M(34) M(35) M(36) M(37) M(38) M(39) M(40) M(41) M(42) M(43) M(44) M(45) M(46) M(47)
#define RPT32A(M) M(0) M(1) M(2) M(3) M(4) M(5) M(6) M(7) M(8) M(9) M(10) M(11) M(12) M(13) M(14) M(15) \
                  M(16) M(17) M(18) M(19) M(20) M(21) M(22) M(23) M(24) M(25) M(26) M(27) M(28) M(29) M(30) M(31)
#define RPT16V(M) M(32) M(33) M(34) M(35) M(36) M(37) M(38) M(39) M(40) M(41) M(42) M(43) M(44) M(45) M(46) M(47)

#define DECLB(i) h8v b##i;
// frag i: tile tt=i>>3 (global tile 6*wv+tt), chunk c=i&7.
// lane: row = 16*(6*wv+tt) + lcol, k0 = 32*c + lg8.
#define LOADB(i) { const float* p_ = Whh + (size_t)(16 * (6 * wv + ((i) >> 3)) + lcol) * 256 + 32 * ((i) & 7) + lg8; \
  h8v v_; v_[0] = (_Float16)p_[0]; v_[1] = (_Float16)p_[1]; v_[2] = (_Float16)p_[2]; v_[3] = (_Float16)p_[3]; \
  v_[4] = (_Float16)p_[4]; v_[5] = (_Float16)p_[5]; v_[6] = (_Float16)p_[6]; v_[7] = (_Float16)p_[7]; b##i = v_; }
#define KEEPA(i) asm volatile("" : "+a"(b##i));
#define KEEPV(i) asm volatile("" : "+v"(b##i));

// v_mfma D, A, B, C (C folded into D). B from AGPR (MFA) or VGPR (MFV).
#define MFA(d_, b_, a_) asm("v_mfma_f32_16x16x32_f16 %0, %1, %2, %0" : "+v"(d_) : "v"(a_), "a"(b_));
#define MFV(d_, b_, a_) asm("v_mfma_f32_16x16x32_f16 %0, %1, %2, %0" : "+v"(d_) : "v"(a_), "v"(b_));
// chunk c: one broadcast A-frag (8 h values, same for all lanes in a k-group),
// 6 MFMAs (tiles 0..5 of this wave). Frag indices: tt*8+c.
#define CHUNK(c_, f0, f1, f2, f3, f4, f5) { \
  h8v a_ = *(const h8v*)(hbuf + 32 * (c_) + lg8); \
  MFA(d0, f0, a_) MFA(d1, f1, a_) MFA(d2, f2, a_) MFA(d3, f3, a_) \
  MFV(d4, f4, a_) MFV(d5, f5, a_) }

template <int ROLE>
__device__ __forceinline__ void gru_scan_dev(char* __restrict__ lds,
                                             const float* __restrict__ Whh, const float* __restrict__ bhh,
                                             const _Float16* __restrict__ giT, _Float16* __restrict__ gout,
                                             int T, int* __restrict__ prog, int* __restrict__ done, int ndone) {
  _Float16* hbuf = (_Float16*)lds;              // 256 f16 (512 B)
  float* ylds = (float*)(lds + 1024);           // 768 f32 (3 KB)
  int j = threadIdx.x;   // 0..511
  int l = j & 63;
  int wv = j >> 6;       // wave 0..7 -> tiles 6wv..6wv+5 (rows 96wv..96wv+96)
  int lcol = l & 15;
  int lg8 = (l >> 4) * 8;
  bool l16 = (l < 16);
  int ju = j & 255;
  bool fin = (j < 256);
  RPT48(DECLB)
  RPT48(LOADB)
  RPT32A(KEEPA)
  RPT16V(KEEPV)
  float bhr = bhh[ju], bhz = bhh[ju + 256], bhn = bhh[ju + 512];
  if (fin) hbuf[ju] = (_Float16)0.f;
  __syncthreads();
  float h = 0.f;
  const _Float16* pR = giT + (size_t)ju * T;
  size_t oZ = (size_t)256 * T, oN = (size_t)512 * T;
  _Float16* gorow = gout + (size_t)ju * T;
  int ybase = 96 * wv + lcol;
  int NC = (T + GCHUNK - 1) / GCHUNK;
  for (int c = 0; c < NC; ++c) {
    int cb = c * GCHUNK;
    int ce = min(cb + GCHUNK, T);
    if (j == 0) {
      while (__hip_atomic_load(&done[c], __ATOMIC_RELAXED, __HIP_MEMORY_SCOPE_AGENT) < ndone)
        __builtin_amdgcn_s_sleep(32);
    }
    __syncthreads();
    __threadfence();   // acquire: invalidate caches before reading the chunk
    h4v cR = {}, cZ = {}, cN = {};
    if (fin) {
      cR = *(const h4v*)(pR + cb);
      cZ = *(const h4v*)(pR + oZ + cb);
      cN = *(const h4v*)(pR + oN + cb);
    }
    for (int t0 = cb; t0 < ce; t0 += 4) {
      h4v nR = cR, nZ = cZ, nN = cN;
      if (fin && t0 + 4 < ce) {   // prefetch confined to chunk
        nR = *(const h4v*)(pR + t0 + 4);
        nZ = *(const h4v*)(pR + oZ + t0 + 4);
        nN = *(const h4v*)(pR + oN + t0 + 4);
      }
      h4v sb;
#pragma unroll
      for (int u = 0; u < 4; ++u) {
        f4v d0 = {}, d1 = {}, d2 = {}, d3 = {}, d4 = {}, d5 = {};
        CHUNK(0, b0, b8, b16, b24, b32, b40)
        CHUNK(1, b1, b9, b17, b25, b33, b41)
        CHUNK(2, b2, b10, b18, b26, b34, b42)
        CHUNK(3, b3, b11, b19, b27, b35, b43)
        CHUNK(4, b4, b12, b20, b28, b36, b44)
        CHUNK(5, b5, b13, b21, b29, b37, b45)
        CHUNK(6, b6, b14, b22, b30, b38, b46)
        CHUNK(7, b7, b15, b23, b31, b39, b47)
        asm volatile("s_nop 7\n\ts_nop 7");   // MFMA->VALU/DS read hazard
        if (l16) {
          ylds[ybase + 0] = d0[0];
          ylds[ybase + 16] = d1[0];
          ylds[ybase + 32] = d2[0];
          ylds[ybase + 48] = d3[0];
          ylds[ybase + 64] = d4[0];
          ylds[ybase + 80] = d5[0];
        }
        step_barrier();   // y visible to gate threads
        if (fin) {
          float ar = ylds[ju] + bhr;
          float az = ylds[256 + ju] + bhz;
          float an = ylds[512 + ju] + bhn;
          float gir = (float)cR[u], giz = (float)cZ[u], gin = (float)cN[u];
          float r = sigf(gir + ar);
          float zt = sigf(giz + az);
          float nn = tanhfast(gin + r * an);
          h = (1.f - zt) * nn + zt * h;
          sb[u] = (_Float16)h;
          hbuf[ju] = (_Float16)h;
        }
        step_barrier();   // h visible to next step's A-frag reads
      }
      if (fin) *(h4v*)(gorow + t0) = sb;
      cR = nR; cZ = nZ; cN = nN;
    }
    if (ROLE == 0) {
      __threadfence();   // release: drain this thread's g0 stores + L2 wb
      __syncthreads();
      if (j == 0) __hip_atomic_store(&prog[0], c + 1, __ATOMIC_RELAXED, __HIP_MEMORY_SCOPE_AGENT);
    }
  }
}

// gi0 worker: gi0[:,m] = [h2[src[m]], h2[dst[m]], ea[m]] @ Wih0^T + bih0  (K=515)
// As: 16x64 floats (stride 64), Bs: 16x66 floats (stride 66), carved from pool.
__device__ __forceinline__ void gi0_worker(float* __restrict__ As, float* __restrict__ Bs,
                                           const float* __restrict__ h2, const int* __restrict__ src,
                                           const int* __restrict__ dst, const float* __restrict__ ea,
                                           const float* __restrict__ W, const float* __restrict__ bias,
                                           _Float16* __restrict__ giT, int T, int w,
                                           int* __restrict__ done, int NC) {
  int tid = threadIdx.x;
  int lk = tid >> 5, lm2 = (tid & 31) * 2;   // A load: [k][m], 2 m's per thread
  int bn = tid >> 3, bk2 = (tid & 7) * 2;    // B load: [k][n], 2 k's per thread
  int tm = (tid >> 4) * 2, tn = (tid & 15) * 4;
  for (int c = 0; c < NC; ++c) {
    int cb = c * GCHUNK;
    int clen = min(GCHUNK, T - cb);
    int mt = (clen + 63) >> 6;
    int ntile = mt * 12;   // 768/64 feature tiles
    for (int tile = w; tile < ntile; tile += NW0) {
      int m0 = cb + (tile % mt) * 64;
      int n0 = (tile / mt) * 64;
      int mA0 = m0 + lm2, mA1 = mA0 + 1;
      int s0 = (mA0 < T) ? src[mA0] : 0, d0 = (mA0 < T) ? dst[mA0] : 0;
      int s1 = (mA1 < T) ? src[mA1] : 0, d1 = (mA1 < T) ? dst[mA1] : 0;
      float acc[2][4] = {};
      for (int k0 = 0; k0 < 515; k0 += 16) {
        int k = k0 + lk;
        float a0, a1;
        if (k < 256) {
          a0 = h2[(size_t)s0 * 256 + k];
          a1 = h2[(size_t)s1 * 256 + k];
        } else if (k < 512) {
          a0 = h2[(size_t)d0 * 256 + (k - 256)];
          a1 = h2[(size_t)d1 * 256 + (k - 256)];
        } else {
          a0 = (k < 515 && mA0 < T) ? ea[(size_t)mA0 * 3 + (k - 512)] : 0.f;
          a1 = (k < 515 && mA1 < T) ? ea[(size_t)mA1 * 3 + (k - 512)] : 0.f;
        }
        As[lk * 64 + lm2] = a0;
        As[lk * 64 + lm2 + 1] = a1;
        Bs[bk2 * 66 + bn] = (k0 + bk2 < 515) ? W[(size_t)(n0 + bn) * 515 + k0 + bk2] : 0.f;
        Bs[(bk2 + 1) * 66 + bn] = (k0 + bk2 + 1 < 515) ? W[(size_t)(n0 + bn) * 515 + k0 + bk2 + 1] : 0.f;
        __syncthreads();
#pragma unroll
        for (int kk = 0; kk < 16; ++kk) {
          float a0v = As[kk * 64 + tm], a1v = As[kk * 64 + tm + 1];
          float b0 = Bs[kk * 66 + tn], b1 = Bs[kk * 66 + tn + 1];
          float b2v = Bs[kk * 66 + tn + 2], b3 = Bs[kk * 66 + tn + 3];
          acc[0][0] = fmaf(a0v, b0, acc[0][0]);
          acc[0][1] = fmaf(a0v, b1, acc[0][1]);
          acc[0][2] = fmaf(a0v, b2v, acc[0][2]);
          acc[0][3] = fmaf(a0v, b3, acc[0][3]);
          acc[1][0] = fmaf(a1v, b0, acc[1][0]);
          acc[1][1] = fmaf(a1v, b1, acc[1][1]);
          acc[1][2] = fmaf(a1v, b2v, acc[1][2]);
          acc[1][3] = fmaf(a1v, b3, acc[1][3]);
        }
        __syncthreads();
      }
#pragma unroll
      for (int i = 0; i < 2; ++i) {
        int m = m0 + tm + i;
        if (m < T) {
#pragma unroll
          for (int qq = 0; qq < 4; ++qq)
            giT[(size_t)(n0 + tn + qq) * T + m] = (_Float16)(acc[i][qq] + bias[n0 + tn + qq]);
        }
      }
    }
    __threadfence();   // release: flush gi0 chunk stores
    __syncthreads();
    if (tid == 0) __hip_atomic_fetch_add(&done[c], 1, __ATOMIC_RELAXED, __HIP_MEMORY_SCOPE_AGENT);
  }
}

// gi1 worker: overwrites gi slot c (gi0 consumed) with g0_chunk @ Wih1^T + bih1.
__device__ __forceinline__ void gi1_worker(float* __restrict__ As, float* __restrict__ Bs,
                                           const _Float16* __restrict__ g0, const float* __restrict__ Wih1,
                                           const float* __restrict__ bih1, _Float16* __restrict__ giT,
                                           int T, int w, int* __restrict__ prog, int* __restrict__ done, int NC) {
  int tid = threadIdx.x;
  int lk = tid >> 5, lm = (tid & 31) * 2;
  int bk = (tid & 7) * 2, bn = tid >> 3;
  int tm = (tid >> 4) * 2, tn = (tid & 15) * 4;
  for (int c = 0; c < NC; ++c) {
    if (tid == 0) {
      while (__hip_atomic_load(&prog[0], __ATOMIC_RELAXED, __HIP_MEMORY_SCOPE_AGENT) < c + 1)
        __builtin_amdgcn_s_sleep(32);
    }
    __syncthreads();
    __threadfence();   // acquire: g0 chunk may be stale in this XCD's L2
    int cb = c * GCHUNK;
    int clen = min(GCHUNK, T - cb);
    int mt = (clen + 63) >> 6;
    int ntile = mt * 12;
    for (int tile = w; tile < ntile; tile += NW1) {
      int m0 = cb + (tile % mt) * 64;
      int n0 = (tile / mt) * 64;
      float acc[2][4] = {};
      for (int k0 = 0; k0 < 256; k0 += 16) {
        int m = m0 + lm;
        float ax = 0.f, ay = 0.f;
        if (m + 1 < T) {
          h2v hv = *(const h2v*)(g0 + (size_t)(k0 + lk) * T + m);
          ax = (float)hv.x; ay = (float)hv.y;
        } else if (m < T) {
          ax = (float)g0[(size_t)(k0 + lk) * T + m];
        }
        As[lk * 64 + lm] = ax;
        As[lk * 64 + lm + 1] = ay;
        float2 bv2 = *(const float2*)(Wih1 + (size_t)(n0 + bn) * 256 + k0 + bk);
        Bs[bk * 66 + bn] = bv2.x;
        Bs[(bk + 1) * 66 + bn] = bv2.y;
        __syncthreads();
#pragma unroll
        for (int kk = 0; kk < 16; ++kk) {
          float a0 = As[kk * 64 + tm], a1 = As[kk * 64 + tm + 1];
          float b0 = Bs[kk * 66 + tn], b1 = Bs[kk * 66 + tn + 1];
          float b2v = Bs[kk * 66 + tn + 2], b3 = Bs[kk * 66 + tn + 3];
          acc[0][0] = fmaf(a0, b0, acc[0][0]);
          acc[0][1] = fmaf(a0, b1, acc[0][1]);
          acc[0][2] = fmaf(a0, b2v, acc[0][2]);
          acc[0][3] = fmaf(a0, b3, acc[0][3]);
          acc[1][0] = fmaf(a1, b0, acc[1][0]);
          acc[1][1] = fmaf(a1, b1, acc[1][1]);
          acc[1][2] = fmaf(a1, b2v, acc[1][2]);
          acc[1][3] = fmaf(a1, b3, acc[1][3]);
        }
        __syncthreads();
      }
#pragma unroll
      for (int i = 0; i < 2; ++i) {
        int m = m0 + tm + i;
        if (m < T) {
#pragma unroll
          for (int qq = 0; qq < 4; ++qq)
            giT[(size_t)(n0 + tn + qq) * T + m] = (_Float16)(acc[i][qq] + bih1[n0 + tn + qq]);
        }
      }
    }
    __threadfence();   // release: flush gi1 chunk stores
    __syncthreads();
    if (tid == 0) __hip_atomic_fetch_add(&done[c], 1, __ATOMIC_RELAXED, __HIP_MEMORY_SCOPE_AGENT);
  }
}

// 96 KB pool -> HW max 1 block/CU (validated round-11). Scan weights live
// as MFMA B-fragments: 32 frags AGPR + 16 frags VGPR (256 total regs/thread,
// the round-13-proven configuration) -> zero weight memory traffic.
__global__ __attribute__((amdgpu_flat_work_group_size(512, 512), amdgpu_waves_per_eu(2, 2)))
void k_fused_gru(const float* __restrict__ Whh0, const float* __restrict__ bhh0,
                 const float* __restrict__ Whh1, const float* __restrict__ bhh1,
                 const float* __restrict__ h2, const int* __restrict__ src,
                 const int* __restrict__ dst, const float* __restrict__ ea,
                 const float* __restrict__ Wih0, const float* __restrict__ bih0,
                 const float* __restrict__ Wih1, const float* __restrict__ bih1,
                 _Float16* __restrict__ gi, _Float16* __restrict__ g0,
                 _Float16* __restrict__ g1, int T, int* __restrict__ flags,
                 int NC) {
  __shared__ __align__(16) char lds_pool[LDS_POOL_BYTES];
  int b = blockIdx.x;
  int* done0 = flags + 8;
  int* done1 = flags + 8 + NC;
  if (b == 0)
    gru_scan_dev<0>(lds_pool, Whh0, bhh0, gi, g0, T, flags, done0, NW0);
  else if (b == 1)
    gru_scan_dev<1>(lds_pool, Whh1, bhh1, gi, g1, T, flags, done1, NW1);
  else if (b < 2 + NW0)
    gi0_worker((float*)lds_pool, (float*)(lds_pool + 16 * 64 * 4),
               h2, src, dst, ea, Wih0, bih0, gi, T, b - 2, done0, NC);
  else
    gi1_worker((float*)lds_pool, (float*)(lds_pool + 16 * 64 * 4),
               g0, Wih1, bih1, gi, T, b - 2 - NW0, flags, done1, NC);
}

// ---------------- final MLP: out[t] = Wlin2 . relu(Wlin1 . g1_t + blin1) + blin2 ----------------

__global__ __launch_bounds__(128) void k_final(const _Float16* __restrict__ g1T, const float* __restrict__ Wlin1,
                                               const float* __restrict__ blin1, const float* __restrict__ Wlin2,
                                               const float* __restrict__ blin2, float* __restrict__ out, int E) {
  int j = threadIdx.x;  // 0..127
  float w[256];
#pragma unroll
  for (int k = 0; k < 256; ++k) w[k] = Wlin1[(size_t)j * 256 + k];
  float bj = blin1[j], w2j = Wlin2[j], b2v = blin2[0];
  __shared__ float gsf[256];
  __shared__ float red[128];
  for (int t = blockIdx.x; t < E; t += gridDim.x) {
    gsf[j] = (float)g1T[(size_t)j * E + t];
    gsf[j + 128] = (float)g1T[(size_t)(j + 128) * E + t];
    __syncthreads();
    float acc = 0.f;
#pragma unroll
    for (int k = 0; k < 256; ++k) acc = fmaf(w[k], gsf[k], acc);
    float v = fmaxf(acc + bj, 0.f) * w2j;
    red[j] = v;
    __syncthreads();
    for (int s = 64; s > 0; s >>= 1) {
      if (j < s) red[j] += red[j + s];
      __syncthreads();
    }
    if (j == 0) out[t] = red[0] + b2v;
    __syncthreads();
  }
}

// ---------------- launch ----------------

extern "C" void kernel_launch(void* const* d_in, const int* in_sizes, int n_in,
                              void* d_out, int out_size, void* d_ws, size_t ws_size,
                              hipStream_t stream) {
  (void)n_in; (void)out_size; (void)ws_size;
  const float* x = (const float*)d_in[0];
  const int* ei = (const int*)d_in[1];
  const float* ea = (const float*)d_in[2];
  const float* W1 = (const float*)d_in[3];
  const float* as1 = (const float*)d_in[4];
  const float* ad1 = (const float*)d_in[5];
  const float* b1 = (const float*)d_in[6];
  const float* gamma1 = (const float*)d_in[7];
  const float* beta1 = (const float*)d_in[8];
  const float* mean1 = (const float*)d_in[9];
  const float* var1 = (const float*)d_in[10];
  const float* W2 = (const float*)d_in[11];
  const float* as2 = (const float*)d_in[12];
  const float* ad2 = (const float*)d_in[13];
  const float* b2 = (const float*)d_in[14];
  const float* gamma2 = (const float*)d_in[15];
  const float* beta2 = (const float*)d_in[16];
  const float* mean2 = (const float*)d_in[17];
  const float* var2 = (const float*)d_in[18];
  const float* Wih0 = (const float*)d_in[19];
  const float* Whh0 = (const float*)d_in[20];
  const float* bih0 = (const float*)d_in[21];
  const float* bhh0 = (const float*)d_in[22];
  const float* Wih1 = (const float*)d_in[23];
  const float* Whh1 = (const float*)d_in[24];
  const float* bih1 = (const float*)d_in[25];
  const float* bhh1 = (const float*)d_in[26];
  const float* Wlin1 = (const float*)d_in[27];
  const float* blin1 = (const float*)d_in[28];
  const float* Wlin2 = (const float*)d_in[29];
  const float* blin2 = (const float*)d_in[30];

  int N = in_sizes[0];
  int E = in_sizes[1] / 2;
  const int* src = ei;
  const int* dst = ei + E;

  char* wsp = (char*)d_ws;
  size_t off = 0;
  auto carve = [&](size_t bytes) -> void* {
    void* p = wsp + off;
    off = (off + bytes + 255) & ~(size_t)255;
    return p;
  };
  float* c12 = (float*)carve(2 * sizeof(float));
  float* a1s = (float*)carve((size_t)N * 4);
  float* a1d = (float*)carve((size_t)N * 4);
  unsigned* m1 = (unsigned*)carve((size_t)N * 4);
  float* z1 = (float*)carve((size_t)N * 4);
  float* uacc = (float*)carve((size_t)N * 4);
  float* h1 = (float*)carve((size_t)N * 256 * 4);
  float* xw2 = (float*)carve((size_t)N * 256 * 4);
  float* a2s = (float*)carve((size_t)N * 4);
  float* a2d = (float*)carve((size_t)N * 4);
  unsigned* m2 = (unsigned*)carve((size_t)N * 4);
  float* z2 = (float*)carve((size_t)N * 4);
  float* acc2 = (float*)carve((size_t)N * 256 * 4);          // becomes h2 in-place
  _Float16* gi = (_Float16*)carve((size_t)E * 768 * 2);      // feature-major [768, E]; gi0 then gi1 in place, chunkwise
  _Float16* g0 = (_Float16*)carve((size_t)E * 256 * 2);      // feature-major [256, E]
  _Float16* g1 = (_Float16*)carve((size_t)E * 256 * 2);      // feature-major [256, E]
  int NCh = (E + GCHUNK - 1) / GCHUNK;
  int flagN = 8 + 2 * NCh;                                   // [0]=prog0, done0[NC], done1[NC]
  int* flags = (int*)carve((size_t)flagN * 4);

  hipMemsetAsync(m1, 0, (size_t)N * 4, stream);
  hipMemsetAsync(z1, 0, (size_t)N * 4, stream);
  hipMemsetAsync(uacc, 0, (size_t)N * 4, stream);
  hipMemsetAsync(m2, 0, (size_t)N * 4, stream);
  hipMemsetAsync(z2, 0, (size_t)N * 4, stream);
  hipMemsetAsync(acc2, 0, (size_t)N * 256 * 4, stream);
  hipMemsetAsync(flags, 0, (size_t)flagN * 4, stream);

  int eb = (E + N + 255) / 256;

  k_prep_c<<<1, 256, 0, stream>>>(W1, as1, ad1, c12);
  k_a1<<<(N + 255) / 256, 256, 0, stream>>>(x, c12, a1s, a1d, N);
  k_edge_max<<<eb, 256, 0, stream>>>(a1s, a1d, m1, src, dst, E, N);
  k_gat1_edge_sum<<<eb, 256, 0, stream>>>(a1s, a1d, m1, src, dst, x, z1, uacc, E, N);
  k_gat1_node<<<N, 256, 0, stream>>>(uacc, z1, W1, b1, gamma1, beta1, mean1, var1, h1);

  dim3 gx((N + BM - 1) / BM, 256 / BN);
  k_gemm_f32<<<gx, 256, 0, stream>>>(h1, W2, xw2, N, 256, 256);
  k_rowdots<<<N, 256, 0, stream>>>(xw2, as2, ad2, a2s, a2d);
  k_edge_max<<<eb, 256, 0, stream>>>(a2s, a2d, m2, src, dst, E, N);
  k_gat2_scatter<<<4096, 256, 0, stream>>>(a2s, a2d, m2, src, dst, xw2, z2, acc2, E, N);
  k_gat2_node<<<N, 256, 0, stream>>>(acc2, z2, b2, gamma2, beta2, mean2, var2);

  // fused pipelined GRU: gi0 workers feed scan0; gi1 workers feed scan1.
  k_fused_gru<<<NBLK, 512, 0, stream>>>(Whh0, bhh0, Whh1, bhh1, acc2, src, dst, ea,
                                        Wih0, bih0, Wih1, bih1, gi, g0, g1, E, flags, NCh);

  k_final<<<1024, 128, 0, stream>>>(g1, Wlin1, blin1, Wlin2, blin2, (float*)d_out, E);
}